// Round 1
// baseline (23514.056 us; speedup 1.0000x reference)
//
#include <hip/hip_runtime.h>

#define VOCAB 50257
#define EMBED 512
#define HIDDEN 1024
#define SEQLEN 512
#define XDIM 1024  // 2*EMBED

typedef unsigned long long u64;
typedef unsigned int u32;

// monotone mapping float -> u32 (order-preserving for all finite floats)
__device__ __forceinline__ u32 fmono(float f) {
  u32 b = __float_as_uint(f);
  return b ^ ((b & 0x80000000u) ? 0xFFFFFFFFu : 0x80000000u);
}

__device__ __forceinline__ float wave_reduce_sum(float v) {
  #pragma unroll
  for (int off = 32; off > 0; off >>= 1) v += __shfl_down(v, off);
  return v;
}

__global__ void init_state(const float* __restrict__ h0, const float* __restrict__ c0,
                           float* __restrict__ hbufs, float* __restrict__ cbufs) {
  int i = threadIdx.x;
  if (i < HIDDEN) {
    hbufs[i] = h0[i];
    cbufs[i] = c0[i];
  }
}

// One step of the LSTM cell. 256 blocks x 256 threads; each wave owns one hidden unit j.
// Also: finalizes previous step's argmax (reduce 256 partial slots), resets this step's slots.
__global__ __launch_bounds__(256)
void lstm_step(const float* __restrict__ emb,
               const float* __restrict__ wih, const float* __restrict__ whh,
               const float* __restrict__ bih, const float* __restrict__ bhh,
               const int* __restrict__ seq,
               float* __restrict__ hbufs, float* __restrict__ cbufs,
               u64* __restrict__ partials, int t) {
  __shared__ float xs[XDIM];
  __shared__ float hs[HIDDEN];
  __shared__ u64 red[4];
  __shared__ int ptok_s;

  const int tid = threadIdx.x;
  const int lane = tid & 63;
  const int wid = tid >> 6;

  const float* hin = hbufs + (t & 1) * HIDDEN;
  const float* cin = cbufs + (t & 1) * HIDDEN;
  float* hout = hbufs + ((t + 1) & 1) * HIDDEN;
  float* cout = cbufs + ((t + 1) & 1) * HIDDEN;

  // ---- previous-step argmax from partials[(t-1)&1] ----
  int ptok = -1;
  if (t > 0) {
    const u64* part = partials + ((t + 1) & 1) * 256;  // (t-1)&1 == (t+1)&1
    u64 v = part[tid];
    #pragma unroll
    for (int off = 32; off > 0; off >>= 1) {
      u64 o = __shfl_down(v, off);
      if (o > v) v = o;
    }
    if (lane == 0) red[wid] = v;
    __syncthreads();
    if (tid == 0) {
      u64 m = red[0];
      if (red[1] > m) m = red[1];
      if (red[2] > m) m = red[2];
      if (red[3] > m) m = red[3];
      ptok_s = VOCAB - (int)(u32)(m & 0xFFFFFFFFu);
    }
    __syncthreads();
    ptok = ptok_s;
  }

  // reset this step's partial slots (block 0 only; B launches after all of A)
  if (blockIdx.x == 0) {
    partials[(t & 1) * 256 + tid] = 0ull;
  }

  // ---- stage x = [prev_embed, tok_embed] and h into LDS ----
  const int tok = seq[t];
  for (int i = tid; i < EMBED; i += 256) {
    xs[i] = (t == 0) ? 0.0f : emb[(size_t)ptok * EMBED + i];
    xs[EMBED + i] = emb[(size_t)tok * EMBED + i];
  }
  for (int i = tid; i < HIDDEN; i += 256) hs[i] = hin[i];
  __syncthreads();

  // ---- gates: each wave computes rows {j, j+H, j+2H, j+3H} ----
  const int j = blockIdx.x * 4 + wid;
  float acc[4];
  #pragma unroll
  for (int g = 0; g < 4; ++g) {
    const float4* wx = (const float4*)(wih + (size_t)(g * HIDDEN + j) * XDIM);
    const float4* wh = (const float4*)(whh + (size_t)(g * HIDDEN + j) * HIDDEN);
    float a = 0.f;
    #pragma unroll
    for (int i = 0; i < 4; ++i) {
      const int k = lane + i * 64;  // float4 index, 0..255
      float4 w4 = wx[k];
      float4 x4 = *((const float4*)&xs[k * 4]);
      a += w4.x * x4.x + w4.y * x4.y + w4.z * x4.z + w4.w * x4.w;
      float4 v4 = wh[k];
      float4 h4 = *((const float4*)&hs[k * 4]);
      a += v4.x * h4.x + v4.y * h4.y + v4.z * h4.z + v4.w * h4.w;
    }
    acc[g] = wave_reduce_sum(a);
  }

  if (lane == 0) {
    float gi = acc[0] + bih[j] + bhh[j];
    float gf = acc[1] + bih[HIDDEN + j] + bhh[HIDDEN + j];
    float gg = acc[2] + bih[2 * HIDDEN + j] + bhh[2 * HIDDEN + j];
    float go = acc[3] + bih[3 * HIDDEN + j] + bhh[3 * HIDDEN + j];
    float si = 1.0f / (1.0f + expf(-gi));
    float sf = 1.0f / (1.0f + expf(-gf));
    float tg = tanhf(gg);
    float so = 1.0f / (1.0f + expf(-go));
    float c2 = sf * cin[j] + si * tg;
    float h2 = so * tanhf(c2);
    cout[j] = c2;
    hout[j] = h2;
  }
}

// logits = W_lin @ h2 + b_lin; write all logits to out (last step's write survives);
// per-block argmax partial -> atomicMax into 256 slots.
__global__ __launch_bounds__(256)
void logits_step(const float* __restrict__ wlin, const float* __restrict__ blin,
                 const float* __restrict__ hbufs, float* __restrict__ out,
                 u64* __restrict__ partials, int t) {
  __shared__ float hs[HIDDEN];
  __shared__ u64 red[4];
  const int tid = threadIdx.x;
  const int lane = tid & 63;
  const int wid = tid >> 6;

  const float* h = hbufs + ((t + 1) & 1) * HIDDEN;
  for (int i = tid; i < HIDDEN; i += 256) hs[i] = h[i];
  __syncthreads();

  const int row = blockIdx.x * 4 + wid;
  u64 pk = 0ull;
  if (row < VOCAB) {
    const float4* wr = (const float4*)(wlin + (size_t)row * HIDDEN);
    float a = 0.f;
    #pragma unroll
    for (int i = 0; i < 4; ++i) {
      const int k = lane + i * 64;
      float4 w4 = wr[k];
      float4 h4 = *((const float4*)&hs[k * 4]);
      a += w4.x * h4.x + w4.y * h4.y + w4.z * h4.z + w4.w * h4.w;
    }
    a = wave_reduce_sum(a);
    if (lane == 0) {
      float logit = a + blin[row];
      out[row] = logit;
      // pack: high 32 = monotone(logit); low 32 = VOCAB-row so ties pick smallest row
      pk = ((u64)fmono(logit) << 32) | (u32)(VOCAB - row);
    }
  }
  if (lane == 0) red[wid] = pk;
  __syncthreads();
  if (tid == 0) {
    u64 m = red[0];
    if (red[1] > m) m = red[1];
    if (red[2] > m) m = red[2];
    if (red[3] > m) m = red[3];
    atomicMax(&partials[(t & 1) * 256 + (blockIdx.x & 255)], m);
  }
}

extern "C" void kernel_launch(void* const* d_in, const int* in_sizes, int n_in,
                              void* d_out, int out_size, void* d_ws, size_t ws_size,
                              hipStream_t stream) {
  const int* seq = (const int*)d_in[0];
  const float* h0 = (const float*)d_in[1];
  const float* c0 = (const float*)d_in[2];
  const float* emb = (const float*)d_in[3];
  const float* wih = (const float*)d_in[4];
  const float* whh = (const float*)d_in[5];
  const float* bih = (const float*)d_in[6];
  const float* bhh = (const float*)d_in[7];
  const float* wlin = (const float*)d_in[8];
  const float* blin = (const float*)d_in[9];
  float* out = (float*)d_out;

  // ws layout: partials (2*256 u64 = 4 KB) | hbufs (2*1024 f) | cbufs (2*1024 f)
  u64* partials = (u64*)d_ws;
  float* hbufs = (float*)((char*)d_ws + 4096);
  float* cbufs = hbufs + 2 * HIDDEN;

  init_state<<<1, HIDDEN, 0, stream>>>(h0, c0, hbufs, cbufs);
  for (int t = 0; t < SEQLEN; ++t) {
    lstm_step<<<HIDDEN / 4, 256, 0, stream>>>(emb, wih, whh, bih, bhh, seq,
                                              hbufs, cbufs, partials, t);
    logits_step<<<(VOCAB + 3) / 4, 256, 0, stream>>>(wlin, blin, hbufs, out,
                                                     partials, t);
  }
}